// Round 16
// baseline (166.086 us; speedup 1.0000x reference)
//
#include <hip/hip_runtime.h>

typedef __bf16 bf16_t;
typedef __bf16 bf16x4 __attribute__((ext_vector_type(4)));
typedef __bf16 bf16x8 __attribute__((ext_vector_type(8)));
typedef float f32x4 __attribute__((ext_vector_type(4)));
typedef unsigned int u32x2 __attribute__((ext_vector_type(2)));
typedef unsigned long long u64;

#define MFMA16(a, b, c) __builtin_amdgcn_mfma_f32_16x16x32_bf16((a), (b), (c), 0, 0, 0)

#define LDG2LDS16(g, l)                                                        \
    __builtin_amdgcn_global_load_lds(                                          \
        (const __attribute__((address_space(1))) void*)(g),                    \
        (__attribute__((address_space(3))) void*)(l), 16, 0, 0)

#if __has_builtin(__builtin_amdgcn_exp2f)
#define EXP2(x) __builtin_amdgcn_exp2f(x)
#else
#define EXP2(x) exp2f(x)
#endif

// load 8 consecutive fp32 as bf16x8
__device__ inline bf16x8 load8(const float* p) {
    const f32x4 a = *(const f32x4*)p;
    const f32x4 b = *(const f32x4*)(p + 4);
    bf16x8 r;
#pragma unroll
    for (int i = 0; i < 4; i++) { r[i] = (bf16_t)a[i]; r[4 + i] = (bf16_t)b[i]; }
    return r;
}

__device__ inline u32x2 as2(bf16x4 v) {
    u32x2 r;
    __builtin_memcpy(&r, &v, 8);
    return r;
}

// 8-byte cross-lane shuffle of a packed bf16x4 (fallback path)
__device__ inline bf16x4 shfl4(bf16x4 v, int src) {
    u64 x;
    __builtin_memcpy(&x, &v, 8);
    x = __shfl(x, src, 64);
    bf16x4 r;
    __builtin_memcpy(&r, &x, 8);
    return r;
}

// P C-layout (two bf16x4 regs covering 32 keys) -> PV B-fragment, via 6
// permlane swaps (verified algebra, rounds 0-15), ds_bpermute fallback.
__device__ inline bf16x8 p2pf(bf16x4 pb0, bf16x4 pb1, int quad, int lr) {
    bf16x8 pf;
#if __has_builtin(__builtin_amdgcn_permlane16_swap) && \
    __has_builtin(__builtin_amdgcn_permlane32_swap)
    const u32x2 P0 = as2(pb0);
    const u32x2 P1 = as2(pb1);
    const u32x2 s1a = __builtin_amdgcn_permlane16_swap(P0[0], P0[1], false, false);
    const u32x2 s1b = __builtin_amdgcn_permlane16_swap(P1[0], P1[1], false, false);
    const u32x2 s2a = __builtin_amdgcn_permlane32_swap(s1a[0], s1b[0], false, false);
    const u32x2 s2b = __builtin_amdgcn_permlane32_swap(s1a[1], s1b[1], false, false);
    const u32x2 s3a = __builtin_amdgcn_permlane16_swap(s2a[0], s2a[1], false, false);
    const u32x2 s3b = __builtin_amdgcn_permlane16_swap(s2b[0], s2b[1], false, false);
    const unsigned pfd[4] = {s3a[0], s3a[1], s3b[0], s3b[1]};
    __builtin_memcpy(&pf, pfd, 16);
#else
    const int srcLow = ((quad & 1) << 5) + lr;
    const int srcHigh = srcLow + 16;
    const bool loSel = (quad < 2);
    const bf16x4 a0 = shfl4(pb0, srcLow);
    const bf16x4 a1 = shfl4(pb1, srcLow);
    const bf16x4 b0 = shfl4(pb0, srcHigh);
    const bf16x4 b1 = shfl4(pb1, srcHigh);
    const bf16x4 lo = loSel ? a0 : a1;
    const bf16x4 hi = loSel ? b0 : b1;
#pragma unroll
    for (int r = 0; r < 4; r++) { pf[r] = lo[r]; pf[4 + r] = hi[r]; }
#endif
    return pf;
}

// ---------------------------------------------------------------------------
// fp32 -> bf16 convert: hs (4194304 el) | wqkv (3145728 el) | wo (1048576 el)
// ---------------------------------------------------------------------------
__global__ __launch_bounds__(256) void convert_kernel(const float* __restrict__ hs,
                                                      const float* __restrict__ wqkv,
                                                      const float* __restrict__ wo,
                                                      bf16_t* __restrict__ outb) {
    const size_t c = ((size_t)blockIdx.x * 256 + threadIdx.x) * 8;
    const float* src;
    size_t off;
    if (c < 4194304) { src = hs; off = c; }
    else if (c < 7340032) { src = wqkv; off = c - 4194304; }
    else { src = wo; off = c - 7340032; }
    *(bf16x8*)(outb + c) = load8(src + off);
}

// ---------------------------------------------------------------------------
// K/V swizzled layouts (MFMA-fragment order -> attn loads are base+lane*16):
//   k_sw: ((bh*128 + t>>4)*2 + (d>>5))*512 + ((t&15)+16*((d&31)>>3))*8 + (d&7)
//   v_sw: ((bh*64 + t>>5)*4 + (d>>4))*512 + ((d&15)+16*((t&31)>>3))*8 + (t&7)
// For a fixed 64-key tile kb, each of K/V occupies a CONTIGUOUS 4096-el (8 KB)
// region at base + kb*4096 -> stageable with 2 global_load_lds sweeps.
// ---------------------------------------------------------------------------

// ---------------------------------------------------------------------------
// QKV projection GEMM (round 16): 128x128 tile, BK=64, 512 threads (8 waves,
// 4M x 2N -> wave = 32x64 output), double-buffered with the r5-verified sync
// skeleton (ran+passed twice): per K-tile { reads kh0+MFMA; reads kh1+MFMA;
// lgkmcnt(0); barrier; STAGE(t+2 -> buf); vmcnt(4); barrier }. The counted
// vmcnt(4) waits tile t+1's 4 loads (issued a FULL iteration earlier) while
// tile t+2's 4 stay in flight — no drain. Grid stays 24x32 = 768 WGs =
// 2 WGs/CU x 8 waves = 16 waves/CU (vs 12 today): r5's structure measured
// 583 TF-per-CU-equivalent (vs m97's 537) but lost to a 0.75-filled grid;
// this shape keeps the engine and fills the machine. Barrier events per WG:
// 16 (vs 32). BK=64 swizzle addressing = round-6 verified (conflicts 0):
// stage SOURCE slot = (tid&7)^(row&7), fragment slot byte = (quad^(lr&7))*16,
// k-half 1 = ^64. Epilogue: wn in {0,64} keeps 64-col alignment -> RoPE/
// scatter code identical to the verified template (IM=2).
// LDS 64 KB -> 2 WGs/CU; launch_bounds(512,4) caps VGPR at 128 (est ~110).
// ---------------------------------------------------------------------------
__global__ __launch_bounds__(512, 4) void gemm1_k64(const bf16_t* __restrict__ A,
                                                    const bf16_t* __restrict__ B,
                                                    bf16_t* __restrict__ q_ws,
                                                    bf16_t* __restrict__ k_ws,
                                                    bf16_t* __restrict__ v_ws,
                                                    const float* __restrict__ cosb,
                                                    const float* __restrict__ sinb) {
    constexpr int K = 1024;
    __shared__ __align__(16) bf16_t As[16384];  // 2 bufs x 128 x 64 (32 KiB)
    __shared__ __align__(16) bf16_t Bs[16384];  // 2 bufs x 128 x 64 (32 KiB)

    const int tid = threadIdx.x;
    const int w = tid >> 6;        // 0..7
    const int lane = tid & 63;
    const int lr = lane & 15;
    const int quad = lane >> 4;
    const int m0 = blockIdx.y * 128;
    const int n0 = blockIdx.x * 128;
    const int wm = (w & 3) * 32;   // 4 M-groups
    const int wn = (w >> 2) * 64;  // 2 N-groups (64-col aligned for epilogue)

    // Staging: thread t covers row (c*64 + tid>>3), 16B slot (tid&7);
    // LDS dest is linear (global_load_lds), SOURCE slot = (tid&7)^(row&7).
    const int trow = tid >> 3;                    // 0..63
    const int slot = (tid & 7) ^ (trow & 7);
    const bf16_t* gA = A + (size_t)(m0 + trow) * K + slot * 8;
    const bf16_t* gB = B + (size_t)(n0 + trow) * K + slot * 8;

    // stage K-tile t into buf b: 2 sweeps of 64 rows each for A and B
#define G1STAGE(t, b)                                                          \
    {                                                                          \
        LDG2LDS16(gA + (size_t)(t) * 64, As + (b) * 8192 + w * 512);           \
        LDG2LDS16(gA + (size_t)64 * K + (size_t)(t) * 64,                      \
                  As + (b) * 8192 + 4096 + w * 512);                           \
        LDG2LDS16(gB + (size_t)(t) * 64, Bs + (b) * 8192 + w * 512);           \
        LDG2LDS16(gB + (size_t)64 * K + (size_t)(t) * 64,                      \
                  Bs + (b) * 8192 + 4096 + w * 512);                           \
    }

    // fragment-read: global slot (kh*4+quad) at LDS byte ((kh*4+quad)^(lr&7))*16
    const int o0 = (quad ^ (lr & 7)) * 16;
    const char* AbB = (const char*)As + (wm + lr) * 128;  // + buf*16384 bytes
    const char* BbB = (const char*)Bs + (wn + lr) * 128;

    f32x4 acc[2][4] = {};

    // prologue: stage tiles 0,1; wait tile 0 only (counted)
    G1STAGE(0, 0);
    G1STAGE(1, 1);
    asm volatile("s_waitcnt vmcnt(4)" ::: "memory");
    __builtin_amdgcn_s_barrier();
    asm volatile("" ::: "memory");

    for (int t = 0; t < 16; t++) {
        const int buf = t & 1;
        const char* pa = AbB + buf * 16384;
        const char* pb = BbB + buf * 16384;
        {
            bf16x8 a0[2], b0[4];
#pragma unroll
            for (int im = 0; im < 2; im++)
                a0[im] = *(const bf16x8*)(pa + im * 2048 + o0);
#pragma unroll
            for (int in = 0; in < 4; in++)
                b0[in] = *(const bf16x8*)(pb + in * 2048 + o0);
            __builtin_amdgcn_s_setprio(1);
#pragma unroll
            for (int im = 0; im < 2; im++)
#pragma unroll
                for (int in = 0; in < 4; in++)
                    acc[im][in] = MFMA16(a0[im], b0[in], acc[im][in]);
            __builtin_amdgcn_s_setprio(0);
        }
        {
            bf16x8 a1[2], b1[4];
#pragma unroll
            for (int im = 0; im < 2; im++)
                a1[im] = *(const bf16x8*)(pa + im * 2048 + (o0 ^ 64));
#pragma unroll
            for (int in = 0; in < 4; in++)
                b1[in] = *(const bf16x8*)(pb + in * 2048 + (o0 ^ 64));
            __builtin_amdgcn_s_setprio(1);
#pragma unroll
            for (int im = 0; im < 2; im++)
#pragma unroll
                for (int in = 0; in < 4; in++)
                    acc[im][in] = MFMA16(a1[im], b1[in], acc[im][in]);
            __builtin_amdgcn_s_setprio(0);
        }
        // all reads of buf complete before any wave overwrites it
        asm volatile("s_waitcnt lgkmcnt(0)" ::: "memory");
        __builtin_amdgcn_s_barrier();
        asm volatile("" ::: "memory");
        if (t < 14) {
            G1STAGE(t + 2, buf);
            // tile t+1's 4 loads (oldest, full iteration of slack) landed;
            // tile t+2's 4 stay in flight
            asm volatile("s_waitcnt vmcnt(4)" ::: "memory");
        } else {
            asm volatile("s_waitcnt vmcnt(0)" ::: "memory");  // drain
        }
        __builtin_amdgcn_s_barrier();
        asm volatile("" ::: "memory");
    }
#undef G1STAGE

    // ---- fused RoPE + scatter epilogue (verified template, IM=2) ----------
    const int j = (n0 + wn) >> 6;  // 0..47: 0..15 Q, 16..31 K, 32..47 V
    if (j < 32) {
        const bool isq = (j < 16);
        const float qs = 0.125f * 1.44269504089f;
#pragma unroll
        for (int im = 0; im < 2; im++) {
#pragma unroll
            for (int r = 0; r < 4; r++) {
                const int m = m0 + wm + im * 16 + quad * 4 + r;
                const int b = m >> 11;
                const int t = m & 2047;
#pragma unroll
                for (int in = 0; in < 2; in++) {
                    const int d = in * 16 + lr;
                    const float x1 = acc[im][in][r];
                    const float x2 = acc[im][in + 2][r];
                    const float c = cosb[t * 64 + d];
                    const float s = sinb[t * 64 + d];
                    float y1 = x1 * c - x2 * s;
                    float y2 = x2 * c + x1 * s;
                    if (isq) {
                        y1 *= qs; y2 *= qs;
                        const size_t base =
                            ((size_t)(b * 16 + j) * 2048 + t) * 64 + d;
                        q_ws[base] = (bf16_t)y1;
                        q_ws[base + 32] = (bf16_t)y2;
                    } else {
                        const int bh = b * 16 + (j - 16);
                        const size_t off =
                            ((size_t)(bh * 128 + (t >> 4)) * 2) * 512 +
                            ((t & 15) + (d >> 3) * 16) * 8 + (d & 7);
                        k_ws[off] = (bf16_t)y1;
                        k_ws[off + 512] = (bf16_t)y2;
                    }
                }
            }
        }
    } else {
#pragma unroll
        for (int im = 0; im < 2; im++)
#pragma unroll
            for (int in = 0; in < 4; in++)
#pragma unroll
                for (int r = 0; r < 4; r++) {
                    const int m = m0 + wm + im * 16 + quad * 4 + r;
                    const int b = m >> 11;
                    const int t = m & 2047;
                    const int d = in * 16 + lr;
                    const int bh = b * 16 + (j - 32);
                    const size_t off =
                        ((size_t)(bh * 64 + (t >> 5)) * 4 + (d >> 4)) * 512 +
                        ((d & 15) + ((t & 31) >> 3) * 16) * 8 + (t & 7);
                    v_ws[off] = (bf16_t)acc[im][in][r];
                }
    }
}

// ---------------------------------------------------------------------------
// GEMM (m97 structure, BK=32) + T2 XOR swizzle — output projection (MODE 0).
// Unchanged from round 15 (verified).
// ---------------------------------------------------------------------------
template <int MODE, int NDIM, int BM>
__global__ __launch_bounds__(256) void gemm_bt(const bf16_t* __restrict__ A,
                                               const bf16_t* __restrict__ B,
                                               float* __restrict__ outp,
                                               bf16_t* __restrict__ q_ws,
                                               bf16_t* __restrict__ k_ws,
                                               bf16_t* __restrict__ v_ws,
                                               const float* __restrict__ cosb,
                                               const float* __restrict__ sinb) {
    constexpr int K = 1024;
    constexpr int IM = BM / 32;
    __shared__ __align__(16) bf16_t As[BM * 32];
    __shared__ __align__(16) bf16_t Bs[128 * 32];

    const int tid = threadIdx.x;
    const int w = tid >> 6;
    const int lane = tid & 63;
    const int lr = lane & 15;
    const int quad = lane >> 4;
    const int m0 = blockIdx.y * BM;
    const int n0 = blockIdx.x * 128;
    const int wm = (w & 1) * (BM / 2);
    const int wn = (w >> 1) * 64;

    const int srow = tid >> 2;
    // source slot pre-swizzled: slot ^ f(row), f(row) = (row>>1)&3
    const int skk = (((tid & 3) ^ ((tid >> 3) & 3)) * 8);
    const bf16_t* gA0 = A + (size_t)(m0 + srow) * K + skk;
    const bf16_t* gA1 = gA0 + (size_t)64 * K;
    const bf16_t* gB0 = B + (size_t)(n0 + srow) * K + skk;
    const bf16_t* gB1 = gB0 + (size_t)64 * K;
    bf16_t* lA0 = As + w * 512;
    bf16_t* lA1 = As + 2048 + w * 512;
    bf16_t* lB0 = Bs + w * 512;
    bf16_t* lB1 = Bs + 2048 + w * 512;

    // fragment-read slot: quad ^ f(row); row low bits = lr -> f = (lr>>1)&3
    const int qsw = (quad ^ ((lr >> 1) & 3)) * 8;

    f32x4 acc[IM][4] = {};

    for (int k0 = 0; k0 < K; k0 += 32) {
        LDG2LDS16(gA0 + k0, lA0);
        if constexpr (BM == 128) LDG2LDS16(gA1 + k0, lA1);
        LDG2LDS16(gB0 + k0, lB0);
        LDG2LDS16(gB1 + k0, lB1);
        __syncthreads();

        bf16x8 af[IM], bfm[4];
#pragma unroll
        for (int im = 0; im < IM; im++)
            af[im] = *(const bf16x8*)&As[(wm + im * 16 + lr) * 32 + qsw];
#pragma unroll
        for (int in = 0; in < 4; in++)
            bfm[in] = *(const bf16x8*)&Bs[(wn + in * 16 + lr) * 32 + qsw];
#pragma unroll
        for (int im = 0; im < IM; im++)
#pragma unroll
            for (int in = 0; in < 4; in++)
                acc[im][in] = MFMA16(af[im], bfm[in], acc[im][in]);
        __syncthreads();
    }

    if constexpr (MODE == 0) {
#pragma unroll
        for (int im = 0; im < IM; im++)
#pragma unroll
            for (int in = 0; in < 4; in++)
#pragma unroll
                for (int r = 0; r < 4; r++) {
                    const int m = m0 + wm + im * 16 + quad * 4 + r;
                    const int n = n0 + wn + in * 16 + lr;
                    outp[(size_t)m * NDIM + n] = acc[im][in][r];
                }
    } else {
        // (unused in this configuration; kept for completeness)
    }
}

// ---------------------------------------------------------------------------
// Flash attention (round 15, verified best): 512 threads / 8 waves per WG.
// Waves 0-3 compute qtA = pr, waves 4-7 compute qtB = 31-pr, concurrently
// sharing one K/V LDS stream (waves 0-3 stage K, 4-7 stage V). Complementary
// pr-fold pr(g)+pr(g+8)=15; bh = blockIdx&31 keeps 4-streams/XCD L2
// residency. Ones-MFMA softmax row-sum. Unchanged from round 15.
// ---------------------------------------------------------------------------
__global__ __launch_bounds__(512, 4) void attn_kernel(const bf16_t* __restrict__ q_ws,
                                                      const bf16_t* __restrict__ k_ws,
                                                      const bf16_t* __restrict__ v_ws,
                                                      bf16_t* __restrict__ ctx) {
    __shared__ __align__(16) bf16_t Ks[2][4096];  // 2 x 8 KB
    __shared__ __align__(16) bf16_t Vs[2][4096];  // 2 x 8 KB

    const int tid = threadIdx.x;
    const int w = tid >> 6;        // 0..7
    const int wq = w & 3;          // quad-wave index within half
    const int lane = tid & 63;
    const int lr = lane & 15;
    const int quad = lane >> 4;
    const int bh = blockIdx.x & 31;
    const int g = blockIdx.x >> 5;               // 0..15
    const int pr = (g < 8) ? g : 23 - g;         // pr(g)+pr(g+8)=15, bijective
    const int qtA = pr;
    const int qtB = 31 - pr;
    const int qtw = (w < 4) ? qtA : qtB;         // this wave's query tile
    const int b = bh >> 4;
    const int hd = bh & 15;

    const bf16_t* kws = k_ws + (size_t)bh * 131072;
    const bf16_t* vws = v_ws + (size_t)bh * 131072;
    const int soff = wq * 512 + lane * 8;  // per-lane element offset in sweep
    const int lo8 = lane * 8;

    bf16x8 ones8;
#pragma unroll
    for (int i = 0; i < 8; i++) ones8[i] = (bf16_t)1.0f;

    // waves 0-3 stage the K tile (2 sweeps each), waves 4-7 the V tile.
#define ASTAGE(kb, bufi)                                                       \
    {                                                                          \
        if (w < 4) {                                                           \
            LDG2LDS16(kws + (size_t)(kb) * 4096 + soff, &Ks[bufi][wq * 512]);  \
            LDG2LDS16(kws + (size_t)(kb) * 4096 + 2048 + soff,                 \
                      &Ks[bufi][2048 + wq * 512]);                             \
        } else {                                                               \
            LDG2LDS16(vws + (size_t)(kb) * 4096 + soff, &Vs[bufi][wq * 512]);  \
            LDG2LDS16(vws + (size_t)(kb) * 4096 + 2048 + soff,                 \
                      &Vs[bufi][2048 + wq * 512]);                             \
        }                                                                      \
    }

    const int trow = qtw * 64 + wq * 16;
    const int query = trow + lr;

    const bf16_t* qb = q_ws + ((size_t)bh * 2048 + trow + lr) * 64 + quad * 8;
    const bf16x8 qlo = *(const bf16x8*)qb;
    const bf16x8 qhi = *(const bf16x8*)(qb + 32);

    f32x4 o[4] = {};
    f32x4 lacc = {};

    // prologue: stage tile 0
    ASTAGE(0, 0);
    asm volatile("s_waitcnt vmcnt(0)" ::: "memory");
    __builtin_amdgcn_s_barrier();
    asm volatile("" ::: "memory");

    for (int kb = 0; kb <= qtB; kb++) {
        const int bufi = kb & 1;
        if (kb < qtB) ASTAGE(kb + 1, bufi ^ 1);

        if (kb <= qtw) {  // wave-uniform guard; barriers stay outside
            // ---- QK^T from LDS ----
            f32x4 s[4];
#pragma unroll
            for (int n = 0; n < 4; n++) {
                const bf16x8 k0 = *(const bf16x8*)&Ks[bufi][(2 * n) * 512 + lo8];
                const bf16x8 k1 =
                    *(const bf16x8*)&Ks[bufi][(2 * n + 1) * 512 + lo8];
                const f32x4 z = {};
                s[n] = MFMA16(k0, qlo, z);
                s[n] = MFMA16(k1, qhi, s[n]);
            }

            const int u0 = kb * 64;
            if (kb == qtw) {  // diagonal: causal mask (key > query)
#pragma unroll
                for (int n = 0; n < 4; n++)
#pragma unroll
                    for (int r = 0; r < 4; r++)
                        if (u0 + n * 16 + quad * 4 + r > query) s[n][r] = -1e9f;
            }

            bf16x4 pb[4];
#pragma unroll
            for (int n = 0; n < 4; n++)
#pragma unroll
                for (int r = 0; r < 4; r++) pb[n][r] = (bf16_t)EXP2(s[n][r]);

#pragma unroll
            for (int hh = 0; hh < 2; hh++) {  // 32-key halves
                const bf16x8 pf = p2pf(pb[2 * hh], pb[2 * hh + 1], quad, lr);
                lacc = MFMA16(ones8, pf, lacc);
#pragma unroll
                for (int n = 0; n < 4; n++) {
                    const bf16x8 vvf =
                        *(const bf16x8*)&Vs[bufi][(hh * 4 + n) * 512 + lo8];
                    o[n] = MFMA16(vvf, pf, o[n]);
                }
            }
        }

        // all LDS reads of bufi done; this wave's stage loads landed
        asm volatile("s_waitcnt lgkmcnt(0) vmcnt(0)" ::: "memory");
        __builtin_amdgcn_s_barrier();
        asm volatile("" ::: "memory");
    }

    // lacc rows are all equal to sum_k P[k][query] -> take reg 0.
    const float inv = 1.0f / fmaxf(lacc[0], 1e-30f);
    const size_t base = ((size_t)b * 2048 + query) * 1024 + hd * 64 + quad * 4;
#pragma unroll
    for (int n = 0; n < 4; n++) {
        bf16x4 ob;
#pragma unroll
        for (int r = 0; r < 4; r++) ob[r] = (bf16_t)(o[n][r] * inv);
        *(bf16x4*)&ctx[base + n * 16] = ob;
    }
#undef ASTAGE
}

// ---------------------------------------------------------------------------
// Launcher. Inputs fp32, output fp32.
// ws bytes: [0,8M) hs_b -> (after gemm1) ctx overlay | [8M,14M) wqkv_b |
//           [14M,16M) wo_b | [16M,24M) q | [24M,32M) k | [32M,40M) v.
// ---------------------------------------------------------------------------
extern "C" void kernel_launch(void* const* d_in, const int* in_sizes, int n_in,
                              void* d_out, int out_size, void* d_ws, size_t ws_size,
                              hipStream_t stream) {
    const float* hs = (const float*)d_in[0];
    const float* cosb = (const float*)d_in[1];
    const float* sinb = (const float*)d_in[2];
    const float* wqkv = (const float*)d_in[3];
    const float* wo = (const float*)d_in[4];
    float* out = (float*)d_out;

    char* ws = (char*)d_ws;
    bf16_t* hs_b = (bf16_t*)(ws);
    bf16_t* wqkv_b = hs_b + 4194304;
    bf16_t* wo_b = hs_b + 7340032;
    bf16_t* q_ws = (bf16_t*)(ws + (size_t)(16u << 20));
    bf16_t* k_ws = (bf16_t*)(ws + (size_t)(24u << 20));
    bf16_t* v_ws = (bf16_t*)(ws + (size_t)(32u << 20));
    bf16_t* ctx = (bf16_t*)(ws);  // overlays hs_b (dead after gemm1)

    const dim3 blk(256);

    // 0) fp32 -> bf16 convert (hs | wqkv | wo packed)
    convert_kernel<<<dim3(4096), blk, 0, stream>>>(hs, wqkv, wo, hs_b);

    // 1) QKV projection + fused RoPE + scatter: M=4096, N=3072, K=1024
    //    128x128 / BK=64 / 8-wave double-buffered counted-vmcnt pipeline.
    gemm1_k64<<<dim3(24, 32), dim3(512), 0, stream>>>(
        hs_b, wqkv_b, q_ws, k_ws, v_ws, cosb, sinb);

    // 2) Flash attention (8-wave shared K/V stream, concurrent halves)
    attn_kernel<<<dim3(512), dim3(512), 0, stream>>>(q_ws, k_ws, v_ws, ctx);

    // 3) Output projection: M=4096, N=1024, K=1024 (BM=64 -> 512 blocks)
    gemm_bt<0, 1024, 64><<<dim3(8, 64), blk, 0, stream>>>(
        ctx, wo_b, out, nullptr, nullptr, nullptr, nullptr, nullptr);
}